// Round 1
// baseline (232.345 us; speedup 1.0000x reference)
//
#include <hip/hip_runtime.h>
#include <hip/hip_bf16.h>

#define C_DIM 8192
#define E_DIM 512

using f32x4 = __attribute__((ext_vector_type(4))) float;
using s16x8 = __attribute__((ext_vector_type(8))) short;

__device__ inline void gload_lds16(const void* g, void* l) {
  __builtin_amdgcn_global_load_lds(
      (const __attribute__((address_space(1))) unsigned*)g,
      (__attribute__((address_space(3))) unsigned*)l, 16, 0, 0);
}

__device__ inline unsigned pack_bf16(float a, float b) {
  unsigned ua = __float_as_uint(a), ub = __float_as_uint(b);
  ua = (ua + 0x7fffu + ((ua >> 16) & 1u)) >> 16;
  ub = (ub + 0x7fffu + ((ub >> 16) & 1u)) >> 16;
  return ua | (ub << 16);
}

// ---------------- Kernel 1: row L2 normalize; write fp32 + bf16 copies ------
__global__ __launch_bounds__(256) void norm_kernel(
    const float* __restrict__ P, float* __restrict__ Pn, unsigned* __restrict__ Pb) {
  int wid = threadIdx.x >> 6, lane = threadIdx.x & 63;
  int row = blockIdx.x * 4 + wid;
  const float4* src = (const float4*)(P + (size_t)row * E_DIM);
  float4 v0 = src[lane], v1 = src[lane + 64];
  float ss = v0.x * v0.x + v0.y * v0.y + v0.z * v0.z + v0.w * v0.w +
             v1.x * v1.x + v1.y * v1.y + v1.z * v1.z + v1.w * v1.w;
  for (int m = 32; m; m >>= 1) ss += __shfl_xor(ss, m);
  float inv = 1.0f / fmaxf(sqrtf(ss), 1e-12f);
  v0.x *= inv; v0.y *= inv; v0.z *= inv; v0.w *= inv;
  v1.x *= inv; v1.y *= inv; v1.z *= inv; v1.w *= inv;
  float4* dst = (float4*)(Pn + (size_t)row * E_DIM);
  dst[lane] = v0; dst[lane + 64] = v1;
  uint2* bd = (uint2*)(Pb + (size_t)row * (E_DIM / 2));
  uint2 b0, b1;
  b0.x = pack_bf16(v0.x, v0.y); b0.y = pack_bf16(v0.z, v0.w);
  b1.x = pack_bf16(v1.x, v1.y); b1.y = pack_bf16(v1.z, v1.w);
  bd[lane] = b0; bd[lane + 64] = b1;
}

// ---------------- Kernel 2: q = sum over rows of Pn  ------------------------
__global__ __launch_bounds__(256) void qsum_kernel(
    const float* __restrict__ Pn, float* __restrict__ q) {
  int col = threadIdx.x;
  int r0 = blockIdx.x * 128;
  float a0 = 0.f, a1 = 0.f;
  for (int r = 0; r < 128; ++r) {
    const float* row = Pn + (size_t)(r0 + r) * E_DIM;
    a0 += row[col];
    a1 += row[col + 256];
  }
  atomicAdd(&q[col], a0);
  atomicAdd(&q[col + 256], a1);
}

// ---------------- Kernel 3: fused Gram + exp-entropy partials ---------------
// G = Pb * Pb^T, per-row Z = sum exp(g), S = sum exp(g)*g (no shift needed:
// all g in [-1,1]).  128x128 tile, BK=64, 4 waves (2x2), 16x16x32 bf16 MFMA.
__global__ __launch_bounds__(256) void gram_kernel(
    const unsigned short* __restrict__ Pb, float* __restrict__ Z, float* __restrict__ S) {
  __shared__ unsigned short As[128 * 64];
  __shared__ unsigned short Bs[128 * 64];
  int bx = blockIdx.x & 63, by = blockIdx.x >> 6;
  int tid = threadIdx.x, wid = tid >> 6, lane = tid & 63;
  int wr = wid >> 1, wc = wid & 1;
  int l15 = lane & 15, lh = lane >> 4;

  f32x4 acc[4][4];
  for (int m = 0; m < 4; ++m)
    for (int n = 0; n < 4; ++n)
      acc[m][n] = (f32x4){0.f, 0.f, 0.f, 0.f};

  for (int kt = 0; kt < 8; ++kt) {
    // stage A and B tiles: each wave stages 4 chunks of 1KB per matrix
    int rs = (lane >> 3);          // 0..7 row within chunk
    int ks = (lane & 7) * 8;       // k element within tile
#pragma unroll
    for (int j = 0; j < 4; ++j) {
      int ci = wid * 4 + j;
      int r = ci * 8 + rs;
      int k = kt * 64 + ks;
      gload_lds16(Pb + ((size_t)(by * 128 + r) * E_DIM + k), (char*)As + ci * 1024);
      gload_lds16(Pb + ((size_t)(bx * 128 + r) * E_DIM + k), (char*)Bs + ci * 1024);
    }
    __syncthreads();

    s16x8 af[4][2], bfr[4][2];
#pragma unroll
    for (int m = 0; m < 4; ++m)
#pragma unroll
      for (int kk = 0; kk < 2; ++kk)
        af[m][kk] = *(const s16x8*)(As + (wr * 64 + m * 16 + l15) * 64 + kk * 32 + lh * 8);
#pragma unroll
    for (int n = 0; n < 4; ++n)
#pragma unroll
      for (int kk = 0; kk < 2; ++kk)
        bfr[n][kk] = *(const s16x8*)(Bs + (wc * 64 + n * 16 + l15) * 64 + kk * 32 + lh * 8);

#pragma unroll
    for (int kk = 0; kk < 2; ++kk)
#pragma unroll
      for (int m = 0; m < 4; ++m)
#pragma unroll
        for (int n = 0; n < 4; ++n)
          acc[m][n] = __builtin_amdgcn_mfma_f32_16x16x32_bf16(
              af[m][kk], bfr[n][kk], acc[m][n], 0, 0, 0);
    __syncthreads();
  }

  // epilogue: per-row partial Z,S; reduce over 16 lanes (cols) + 4 n-frags
  int rowbase = by * 128 + wr * 64;
#pragma unroll
  for (int m = 0; m < 4; ++m) {
#pragma unroll
    for (int reg = 0; reg < 4; ++reg) {
      float z = 0.f, s = 0.f;
#pragma unroll
      for (int n = 0; n < 4; ++n) {
        float g = acc[m][n][reg];
        float e = __expf(g);
        z += e;
        s += e * g;
      }
      for (int msk = 8; msk; msk >>= 1) {
        z += __shfl_xor(z, msk);
        s += __shfl_xor(s, msk);
      }
      if (l15 == 0) {
        int grow = rowbase + m * 16 + lh * 4 + reg;
        atomicAdd(&Z[grow], z);
        atomicAdd(&S[grow], s);
      }
    }
  }
}

// ---------------- Kernel 4: s_j = dot(Pn[j], q) -----------------------------
__global__ __launch_bounds__(256) void ssum_kernel(
    const float* __restrict__ Pn, const float* __restrict__ q, float* __restrict__ s) {
  int wid = threadIdx.x >> 6, lane = threadIdx.x & 63;
  int row = blockIdx.x * 4 + wid;
  const float4* pr = (const float4*)(Pn + (size_t)row * E_DIM);
  const float4* qr = (const float4*)q;
  float4 a0 = pr[lane], a1 = pr[lane + 64];
  float4 q0 = qr[lane], q1 = qr[lane + 64];
  float d = a0.x * q0.x + a0.y * q0.y + a0.z * q0.z + a0.w * q0.w +
            a1.x * q1.x + a1.y * q1.y + a1.z * q1.z + a1.w * q1.w;
  for (int m = 32; m; m >>= 1) d += __shfl_xor(d, m);
  if (lane == 0) s[row] = d;
}

// ---------------- Kernel 5: finalize ----------------------------------------
__device__ inline float bsum(float v, volatile float* red) {
  int lane = threadIdx.x & 63, wid = threadIdx.x >> 6;
  for (int k = 32; k; k >>= 1) v += __shfl_xor(v, k);
  __syncthreads();
  if (lane == 0) red[wid] = v;
  __syncthreads();
  float r = 0.f;
  if (wid == 0) {
    r = (lane < 16) ? red[lane] : 0.f;
    for (int k = 8; k; k >>= 1) r += __shfl_xor(r, k);
  }
  if (threadIdx.x == 0) red[16] = r;
  __syncthreads();
  return red[16];
}

__device__ inline float bmax(float v, volatile float* red) {
  int lane = threadIdx.x & 63, wid = threadIdx.x >> 6;
  for (int k = 32; k; k >>= 1) v = fmaxf(v, __shfl_xor(v, k));
  __syncthreads();
  if (lane == 0) red[wid] = v;
  __syncthreads();
  float r = -3.4e38f;
  if (wid == 0) {
    r = (lane < 16) ? red[lane] : -3.4e38f;
    for (int k = 8; k; k >>= 1) r = fmaxf(r, __shfl_xor(r, k));
  }
  if (threadIdx.x == 0) red[16] = r;
  __syncthreads();
  return red[16];
}

__global__ __launch_bounds__(1024) void final_kernel(
    const float* __restrict__ s, const float* __restrict__ Z,
    const float* __restrict__ S, float* __restrict__ out) {
  __shared__ float red[17];
  int tid = threadIdx.x;

  // entropy of the colsum vector s (with max shift; s can be ~ +-20)
  float m = -3.4e38f;
  for (int i = tid; i < C_DIM; i += 1024) m = fmaxf(m, s[i]);
  m = bmax(m, red);

  float z = 0.f, sw = 0.f;
  for (int i = tid; i < C_DIM; i += 1024) {
    float t = s[i] - m;
    float e = __expf(t);
    z += e;
    sw += e * t;
  }
  z = bsum(z, red);
  sw = bsum(sw, red);
  float H2 = logf(z) - sw / z;

  // mean of per-row entropies
  float h = 0.f;
  for (int i = tid; i < C_DIM; i += 1024) {
    float zi = Z[i];
    h += logf(zi) - S[i] / zi;
  }
  h = bsum(h, red);

  if (tid == 0) out[0] = h / (float)C_DIM + H2;
}

extern "C" void kernel_launch(void* const* d_in, const int* in_sizes, int n_in,
                              void* d_out, int out_size, void* d_ws, size_t ws_size,
                              hipStream_t stream) {
  const float* P = (const float*)d_in[0];
  float* out = (float*)d_out;

  char* ws = (char*)d_ws;
  float* Pn = (float*)(ws);                                   // 16 MB
  unsigned* Pb = (unsigned*)(ws + (size_t)16 * 1024 * 1024);  // 8 MB (bf16)
  float* q = (float*)(ws + (size_t)24 * 1024 * 1024);         // 2 KB
  float* Z = (float*)(ws + (size_t)24 * 1024 * 1024 + 2048);  // 32 KB
  float* S = (float*)(ws + (size_t)24 * 1024 * 1024 + 2048 + 32768);  // 32 KB
  float* s = (float*)(ws + (size_t)24 * 1024 * 1024 + 2048 + 65536);  // 32 KB

  // zero q, Z, S (contiguous 2048 + 32768 + 32768 bytes)
  hipMemsetAsync(q, 0, 2048 + 65536, stream);

  norm_kernel<<<C_DIM / 4, 256, 0, stream>>>(P, Pn, Pb);
  qsum_kernel<<<C_DIM / 128, 256, 0, stream>>>(Pn, q);
  gram_kernel<<<64 * 64, 256, 0, stream>>>((const unsigned short*)Pb, Z, S);
  ssum_kernel<<<C_DIM / 4, 256, 0, stream>>>(Pn, q, s);
  final_kernel<<<1, 1024, 0, stream>>>(s, Z, S, out);
}

// Round 2
// 144.584 us; speedup vs baseline: 1.6070x; 1.6070x over previous
//
#include <hip/hip_runtime.h>
#include <hip/hip_bf16.h>

#define C_DIM 8192
#define E_DIM 512

using f32x4 = __attribute__((ext_vector_type(4))) float;
using s16x8 = __attribute__((ext_vector_type(8))) short;

__device__ inline void gload_lds16(const void* g, void* l) {
  __builtin_amdgcn_global_load_lds(
      (const __attribute__((address_space(1))) unsigned*)g,
      (__attribute__((address_space(3))) unsigned*)l, 16, 0, 0);
}

__device__ inline unsigned pack_bf16(float a, float b) {
  unsigned ua = __float_as_uint(a), ub = __float_as_uint(b);
  ua = (ua + 0x7fffu + ((ua >> 16) & 1u)) >> 16;
  ub = (ub + 0x7fffu + ((ub >> 16) & 1u)) >> 16;
  return ua | (ub << 16);
}

// ---------------- Kernel 1: row L2 normalize; write fp32 + bf16 copies ------
__global__ __launch_bounds__(256) void norm_kernel(
    const float* __restrict__ P, float* __restrict__ Pn, unsigned* __restrict__ Pb) {
  int wid = threadIdx.x >> 6, lane = threadIdx.x & 63;
  int row = blockIdx.x * 4 + wid;
  const float4* src = (const float4*)(P + (size_t)row * E_DIM);
  float4 v0 = src[lane], v1 = src[lane + 64];
  float ss = v0.x * v0.x + v0.y * v0.y + v0.z * v0.z + v0.w * v0.w +
             v1.x * v1.x + v1.y * v1.y + v1.z * v1.z + v1.w * v1.w;
  for (int m = 32; m; m >>= 1) ss += __shfl_xor(ss, m);
  float inv = 1.0f / fmaxf(sqrtf(ss), 1e-12f);
  v0.x *= inv; v0.y *= inv; v0.z *= inv; v0.w *= inv;
  v1.x *= inv; v1.y *= inv; v1.z *= inv; v1.w *= inv;
  float4* dst = (float4*)(Pn + (size_t)row * E_DIM);
  dst[lane] = v0; dst[lane + 64] = v1;
  uint2* bd = (uint2*)(Pb + (size_t)row * (E_DIM / 2));
  uint2 b0, b1;
  b0.x = pack_bf16(v0.x, v0.y); b0.y = pack_bf16(v0.z, v0.w);
  b1.x = pack_bf16(v1.x, v1.y); b1.y = pack_bf16(v1.z, v1.w);
  bd[lane] = b0; bd[lane + 64] = b1;
}

// ---------------- Kernel 2: q = sum over rows of Pn  ------------------------
__global__ __launch_bounds__(256) void qsum_kernel(
    const float* __restrict__ Pn, float* __restrict__ q) {
  int col = threadIdx.x;
  int r0 = blockIdx.x * 128;
  float a0 = 0.f, a1 = 0.f;
  for (int r = 0; r < 128; ++r) {
    const float* row = Pn + (size_t)(r0 + r) * E_DIM;
    a0 += row[col];
    a1 += row[col + 256];
  }
  atomicAdd(&q[col], a0);
  atomicAdd(&q[col + 256], a1);
}

// ---------------- Kernel 3: fused Gram + exp-entropy partials ---------------
// G = Pb * Pb^T symmetric: only upper-triangle 128x128 tiles (bx >= by).
// Each tile adds row partials (Z,S at by-rows) and, when off-diagonal,
// column partials (Z,S at bx-rows, by symmetry).  No max-shift needed:
// all g in [-1,1].  BK=64, 4 waves (2x2), 16x16x32 bf16 MFMA.
// LDS XOR-swizzle: slot s of row r holds column-group s^(r&7); achieved by
// pre-swizzling the GLOBAL source (linear LDS dest for global_load_lds) and
// XOR-ing the same involution into the ds_read address.
__global__ __launch_bounds__(256) void gram_kernel(
    const unsigned short* __restrict__ Pb, float* __restrict__ Z, float* __restrict__ S) {
  __shared__ unsigned short As[128 * 64];
  __shared__ unsigned short Bs[128 * 64];

  // decode triangular block index -> (by, bx), bx >= by
  int i = blockIdx.x;
  float bi = 64.5f - sqrtf(64.5f * 64.5f - 2.0f * (float)i);
  int by = (int)bi;
  if (by < 0) by = 0;
  while (64 * (by + 1) - ((by + 1) * by) / 2 <= i) ++by;
  while (64 * by - (by * (by - 1)) / 2 > i) --by;
  int bx = by + (i - (64 * by - (by * (by - 1)) / 2));
  bool diag = (bx == by);

  int tid = threadIdx.x, wid = tid >> 6, lane = tid & 63;
  int wr = wid >> 1, wc = wid & 1;
  int l15 = lane & 15, lh = lane >> 4;

  f32x4 acc[4][4];
  for (int m = 0; m < 4; ++m)
    for (int n = 0; n < 4; ++n)
      acc[m][n] = (f32x4){0.f, 0.f, 0.f, 0.f};

  int rs = lane >> 3;                              // row within 8-row chunk
  int ksw = (((lane & 7) ^ rs) * 8);               // pre-swizzled col element

  for (int kt = 0; kt < 8; ++kt) {
#pragma unroll
    for (int j = 0; j < 4; ++j) {
      int ci = wid * 4 + j;
      int r = ci * 8 + rs;
      int k = kt * 64 + ksw;
      gload_lds16(Pb + ((size_t)(by * 128 + r) * E_DIM + k), (char*)As + ci * 1024);
      gload_lds16(Pb + ((size_t)(bx * 128 + r) * E_DIM + k), (char*)Bs + ci * 1024);
    }
    __syncthreads();

    s16x8 af[4][2], bfr[4][2];
#pragma unroll
    for (int m = 0; m < 4; ++m)
#pragma unroll
      for (int kk = 0; kk < 2; ++kk) {
        int row = wr * 64 + m * 16 + l15;
        int slot = (kk * 4 + lh) ^ (l15 & 7);
        af[m][kk] = *(const s16x8*)(As + row * 64 + slot * 8);
      }
#pragma unroll
    for (int n = 0; n < 4; ++n)
#pragma unroll
      for (int kk = 0; kk < 2; ++kk) {
        int row = wc * 64 + n * 16 + l15;
        int slot = (kk * 4 + lh) ^ (l15 & 7);
        bfr[n][kk] = *(const s16x8*)(Bs + row * 64 + slot * 8);
      }

#pragma unroll
    for (int kk = 0; kk < 2; ++kk)
#pragma unroll
      for (int m = 0; m < 4; ++m)
#pragma unroll
        for (int n = 0; n < 4; ++n)
          acc[m][n] = __builtin_amdgcn_mfma_f32_16x16x32_bf16(
              af[m][kk], bfr[n][kk], acc[m][n], 0, 0, 0);
    __syncthreads();
  }

  // epilogue: row partials (reduce over l15) + col partials (reduce over lh)
  int rowbase = by * 128 + wr * 64;
  int colbase = bx * 128 + wc * 64;
  float zc[4], sc[4];
#pragma unroll
  for (int n = 0; n < 4; ++n) { zc[n] = 0.f; sc[n] = 0.f; }

#pragma unroll
  for (int m = 0; m < 4; ++m) {
#pragma unroll
    for (int reg = 0; reg < 4; ++reg) {
      float z = 0.f, s = 0.f;
#pragma unroll
      for (int n = 0; n < 4; ++n) {
        float g = acc[m][n][reg];
        float e = __expf(g);
        z += e;
        s += e * g;
        zc[n] += e;
        sc[n] += e * g;
      }
      for (int msk = 8; msk; msk >>= 1) {
        z += __shfl_xor(z, msk);
        s += __shfl_xor(s, msk);
      }
      if (l15 == 0) {
        int grow = rowbase + m * 16 + lh * 4 + reg;
        atomicAdd(&Z[grow], z);
        atomicAdd(&S[grow], s);
      }
    }
  }
  if (!diag) {
#pragma unroll
    for (int n = 0; n < 4; ++n) {
      float z = zc[n], s = sc[n];
      z += __shfl_xor(z, 16); s += __shfl_xor(s, 16);
      z += __shfl_xor(z, 32); s += __shfl_xor(s, 32);
      if (lh == 0) {
        int gcol = colbase + n * 16 + l15;
        atomicAdd(&Z[gcol], z);
        atomicAdd(&S[gcol], s);
      }
    }
  }
}

// ---------------- Kernel 4: s_j = dot(Pn[j], q) -----------------------------
__global__ __launch_bounds__(256) void ssum_kernel(
    const float* __restrict__ Pn, const float* __restrict__ q, float* __restrict__ s) {
  int wid = threadIdx.x >> 6, lane = threadIdx.x & 63;
  int row = blockIdx.x * 4 + wid;
  const float4* pr = (const float4*)(Pn + (size_t)row * E_DIM);
  const float4* qr = (const float4*)q;
  float4 a0 = pr[lane], a1 = pr[lane + 64];
  float4 q0 = qr[lane], q1 = qr[lane + 64];
  float d = a0.x * q0.x + a0.y * q0.y + a0.z * q0.z + a0.w * q0.w +
            a1.x * q1.x + a1.y * q1.y + a1.z * q1.z + a1.w * q1.w;
  for (int m = 32; m; m >>= 1) d += __shfl_xor(d, m);
  if (lane == 0) s[row] = d;
}

// ---------------- Kernel 5: finalize ----------------------------------------
__device__ inline float bsum(float v, volatile float* red) {
  int lane = threadIdx.x & 63, wid = threadIdx.x >> 6;
  for (int k = 32; k; k >>= 1) v += __shfl_xor(v, k);
  __syncthreads();
  if (lane == 0) red[wid] = v;
  __syncthreads();
  float r = 0.f;
  if (wid == 0) {
    r = (lane < 16) ? red[lane] : 0.f;
    for (int k = 8; k; k >>= 1) r += __shfl_xor(r, k);
  }
  if (threadIdx.x == 0) red[16] = r;
  __syncthreads();
  return red[16];
}

__device__ inline float bmax(float v, volatile float* red) {
  int lane = threadIdx.x & 63, wid = threadIdx.x >> 6;
  for (int k = 32; k; k >>= 1) v = fmaxf(v, __shfl_xor(v, k));
  __syncthreads();
  if (lane == 0) red[wid] = v;
  __syncthreads();
  float r = -3.4e38f;
  if (wid == 0) {
    r = (lane < 16) ? red[lane] : -3.4e38f;
    for (int k = 8; k; k >>= 1) r = fmaxf(r, __shfl_xor(r, k));
  }
  if (threadIdx.x == 0) red[16] = r;
  __syncthreads();
  return red[16];
}

__global__ __launch_bounds__(1024) void final_kernel(
    const float* __restrict__ s, const float* __restrict__ Z,
    const float* __restrict__ S, float* __restrict__ out) {
  __shared__ float red[17];
  int tid = threadIdx.x;

  // entropy of the colsum vector s (with max shift; s can be ~ +-20)
  float m = -3.4e38f;
  for (int i = tid; i < C_DIM; i += 1024) m = fmaxf(m, s[i]);
  m = bmax(m, red);

  float z = 0.f, sw = 0.f;
  for (int i = tid; i < C_DIM; i += 1024) {
    float t = s[i] - m;
    float e = __expf(t);
    z += e;
    sw += e * t;
  }
  z = bsum(z, red);
  sw = bsum(sw, red);
  float H2 = logf(z) - sw / z;

  // mean of per-row entropies
  float h = 0.f;
  for (int i = tid; i < C_DIM; i += 1024) {
    float zi = Z[i];
    h += logf(zi) - S[i] / zi;
  }
  h = bsum(h, red);

  if (tid == 0) out[0] = h / (float)C_DIM + H2;
}

extern "C" void kernel_launch(void* const* d_in, const int* in_sizes, int n_in,
                              void* d_out, int out_size, void* d_ws, size_t ws_size,
                              hipStream_t stream) {
  const float* P = (const float*)d_in[0];
  float* out = (float*)d_out;

  char* ws = (char*)d_ws;
  float* Pn = (float*)(ws);                                   // 16 MB
  unsigned* Pb = (unsigned*)(ws + (size_t)16 * 1024 * 1024);  // 8 MB (bf16)
  float* q = (float*)(ws + (size_t)24 * 1024 * 1024);         // 2 KB
  float* Z = (float*)(ws + (size_t)24 * 1024 * 1024 + 2048);  // 32 KB
  float* S = (float*)(ws + (size_t)24 * 1024 * 1024 + 2048 + 32768);  // 32 KB
  float* s = (float*)(ws + (size_t)24 * 1024 * 1024 + 2048 + 65536);  // 32 KB

  // zero q, Z, S (contiguous 2048 + 32768 + 32768 bytes)
  hipMemsetAsync(q, 0, 2048 + 65536, stream);

  norm_kernel<<<C_DIM / 4, 256, 0, stream>>>(P, Pn, Pb);
  qsum_kernel<<<C_DIM / 128, 256, 0, stream>>>(Pn, q);
  gram_kernel<<<2080, 256, 0, stream>>>((const unsigned short*)Pb, Z, S);
  ssum_kernel<<<C_DIM / 4, 256, 0, stream>>>(Pn, q, s);
  final_kernel<<<1, 1024, 0, stream>>>(s, Z, S, out);
}